// Round 6
// baseline (155.897 us; speedup 1.0000x reference)
//
#include <hip/hip_runtime.h>
#include <hip/hip_bf16.h>

// Sparse 3DNA (causal), MI355X. Round 13 (= R12 resubmitted after infra
// failure; source audited for hang/fault paths — none found).
// Revert R10 regressions (qkv back to BM=128 R7; head-mix back to LDS).
// NEW: attn stages the block's K/V neighborhood UNION (55 rows each) into
// LDS via global_load_lds DMA once, then QK^T and PV run from LDS —
// converts 56 latency-exposed gathers/wave into one bulk BW-shaped stage.

constexpr int TFR   = 8;
constexpr int SDIM  = 24;
constexpr int NVID  = TFR * SDIM * SDIM;   // 4608
constexpr int NTOK  = NVID + 1;            // 4609
constexpr int NH    = 8;
constexpr int DM    = 512;
constexpr int NJ    = 28;
constexpr int NUROW = 55;                  // 3*3*6 neighborhood union + bos

typedef __attribute__((ext_vector_type(8))) short bf16x8;
typedef __attribute__((ext_vector_type(8))) unsigned short ushort8;
typedef __attribute__((ext_vector_type(4))) float f32x4;

typedef const __attribute__((address_space(1))) unsigned int* gas_ptr;
typedef __attribute__((address_space(3))) unsigned int* las_ptr;

__device__ __forceinline__ float bf2f(unsigned short u) {
    return __uint_as_float((unsigned)u << 16);
}
__device__ __forceinline__ unsigned short f2bf(float f) {
    __hip_bfloat16 h = __float2bfloat16(f);
    return reinterpret_cast<unsigned short&>(h);
}

// ---------------------------------------------------------------------------
// prep: transpose+cast Wq/Wkv and Wout; straight cast x -> xb (bf16).
// ---------------------------------------------------------------------------
__global__ __launch_bounds__(256)
void prep_w(const float* __restrict__ Wq, const float* __restrict__ Wkv,
            const float* __restrict__ Wout, const float* __restrict__ x,
            __hip_bfloat16* __restrict__ Wqkvt, __hip_bfloat16* __restrict__ Woutt,
            __hip_bfloat16* __restrict__ xb)
{
    const int tid = threadIdx.x;
    int tb = blockIdx.x;

    if (tb >= 1024) {                       // ---- x cast: fp32 -> bf16 ----
        const size_t base = (size_t)(tb - 1024) * 2048 + (size_t)tid * 8;
        if (base < (size_t)NTOK * DM) {
            const float4 f0 = *(const float4*)(x + base);
            const float4 f1 = *(const float4*)(x + base + 4);
            unsigned short v[8] = { f2bf(f0.x), f2bf(f0.y), f2bf(f0.z), f2bf(f0.w),
                                    f2bf(f1.x), f2bf(f1.y), f2bf(f1.z), f2bf(f1.w) };
            *(ushort8*)(xb + base) = *(const ushort8*)v;
        }
        return;
    }

    __shared__ float t[32][33];
    const float* W; __hip_bfloat16* Wt; int Nd, tX, rowOff;
    if (tb < 256)      { W = Wq;   Wt = Wqkvt; Nd = 512;  tX = 16; rowOff = 0;   }
    else if (tb < 768) { tb -= 256; W = Wkv;  Wt = Wqkvt; Nd = 1024; tX = 32; rowOff = 512; }
    else               { tb -= 768; W = Wout; Wt = Woutt; Nd = 512;  tX = 16; rowOff = 0;   }
    const int n0 = (tb % tX) * 32, k0 = (tb / tX) * 32;
    const int r  = tid >> 3;
    const int c4 = (tid & 7) * 4;
    const float4 v = *(const float4*)(W + (size_t)(k0 + r) * Nd + n0 + c4);
    t[r][c4 + 0] = v.x; t[r][c4 + 1] = v.y; t[r][c4 + 2] = v.z; t[r][c4 + 3] = v.w;
    __syncthreads();
    #pragma unroll
    for (int j = 0; j < 4; ++j)
        Wt[(size_t)(rowOff + n0 + r) * 512 + k0 + c4 + j] = __float2bfloat16(t[c4 + j][r]);
}

// ---------------------------------------------------------------------------
// QKV GEMM (R7-proven): BM=BN=128, BK=64, 444 blocks, XCD-chunked, both
// operands global_load_lds + XOR swizzle.
// ---------------------------------------------------------------------------
__global__ __launch_bounds__(256)
void gemm_qkv(const __hip_bfloat16* __restrict__ Ab, const __hip_bfloat16* __restrict__ Bt,
              float* __restrict__ Cq, __hip_bfloat16* __restrict__ Ckv, int M)
{
    constexpr int BM = 128, BN = 128, BK = 64, K = 512;
    __shared__ __align__(16) short As[BM * BK];
    __shared__ __align__(16) short Bs[BN * BK];

    const int tid  = threadIdx.x;
    const int bid  = blockIdx.x;
    const int xcd  = bid & 7, pos = bid >> 3;
    const int L    = (xcd < 4) ? xcd * 56 + pos : 224 + (xcd - 4) * 55 + pos;
    const int m0   = (L / 12) * BM;
    const int n0   = (L % 12) * BN;

    const int lane = tid & 63;
    const int wave = tid >> 6;
    const int wm   = (wave >> 1) * 64;
    const int wn   = (wave & 1) * 64;
    const int col  = lane & 15;
    const int quad = lane >> 4;

    f32x4 acc[4][4] = {};

    for (int k0 = 0; k0 < K; k0 += BK) {
        #pragma unroll
        for (int it = 0; it < 4; ++it) {
            const int idx = it * 256 + tid;
            const int r   = idx >> 3;
            const int u   = (idx & 7) ^ (r & 7);
            const int gm  = (m0 + r < M) ? (m0 + r) : (M - 1);
            const __hip_bfloat16* gp = Ab + (size_t)gm * K + k0 + u * 8;
            __builtin_amdgcn_global_load_lds(
                (gas_ptr)gp, (las_ptr)&As[(it * 256 + wave * 64) * 8], 16, 0, 0);
        }
        #pragma unroll
        for (int it = 0; it < 4; ++it) {
            const int idx = it * 256 + tid;
            const int r   = idx >> 3;
            const int u   = (idx & 7) ^ (r & 7);
            const __hip_bfloat16* gp = Bt + (size_t)(n0 + r) * K + k0 + u * 8;
            __builtin_amdgcn_global_load_lds(
                (gas_ptr)gp, (las_ptr)&Bs[(it * 256 + wave * 64) * 8], 16, 0, 0);
        }
        __syncthreads();

        #pragma unroll
        for (int ks = 0; ks < 2; ++ks) {
            bf16x8 af[4], bfr[4];
            #pragma unroll
            for (int mt = 0; mt < 4; ++mt) {
                const int r = wm + mt * 16 + col;
                const int u = (ks * 4 + quad) ^ (r & 7);
                af[mt] = *(const bf16x8*)(&As[r * BK + u * 8]);
            }
            #pragma unroll
            for (int nt = 0; nt < 4; ++nt) {
                const int r = wn + nt * 16 + col;
                const int u = (ks * 4 + quad) ^ (r & 7);
                bfr[nt] = *(const bf16x8*)(&Bs[r * BK + u * 8]);
            }
            #pragma unroll
            for (int mt = 0; mt < 4; ++mt)
                #pragma unroll
                for (int nt = 0; nt < 4; ++nt)
                    acc[mt][nt] = __builtin_amdgcn_mfma_f32_16x16x32_bf16(
                        af[mt], bfr[nt], acc[mt][nt], 0, 0, 0);
        }
        __syncthreads();
    }

    const bool isQ = (n0 < 512);
    #pragma unroll
    for (int mt = 0; mt < 4; ++mt) {
        #pragma unroll
        for (int r = 0; r < 4; ++r) {
            const int row = m0 + wm + mt * 16 + quad * 4 + r;
            if (row >= M) continue;
            #pragma unroll
            for (int nt = 0; nt < 4; ++nt) {
                const int cg = n0 + wn + nt * 16 + col;
                const float v = acc[mt][nt][r];
                if (isQ) Cq[(size_t)row * 512 + cg] = v * 0.125f;
                else     Ckv[(size_t)row * 1024 + (cg - 512)] = __float2bfloat16(v);
            }
        }
    }
}

// ---------------------------------------------------------------------------
// out-proj GEMM (R7-proven): BM=BN=64, 584 blocks, XCD-chunked.
// ---------------------------------------------------------------------------
__global__ __launch_bounds__(256)
void gemm_out(const __hip_bfloat16* __restrict__ A, const __hip_bfloat16* __restrict__ Bt,
              float* __restrict__ C, int M, const float* __restrict__ bias)
{
    constexpr int BM = 64, BN = 64, BK = 64, K = 512;
    __shared__ __align__(16) short As[BM * BK];
    __shared__ __align__(16) short Bs[BN * BK];

    const int tid  = threadIdx.x;
    const int bid  = blockIdx.x;
    const int L    = (bid & 7) * 73 + (bid >> 3);   // 584 = 8*73 exact
    const int m0   = (L >> 3) * BM;
    const int n0   = (L & 7) * BN;
    const int lane = tid & 63;
    const int wave = tid >> 6;
    const int wm   = (wave >> 1) * 32;
    const int wn   = (wave & 1) * 32;
    const int col  = lane & 15;
    const int quad = lane >> 4;

    f32x4 acc[2][2] = {};

    for (int k0 = 0; k0 < K; k0 += BK) {
        #pragma unroll
        for (int it = 0; it < 2; ++it) {
            const int idx = it * 256 + tid;
            const int r   = idx >> 3;
            const int u   = (idx & 7) ^ (r & 7);
            const int gm  = (m0 + r < M) ? (m0 + r) : (M - 1);
            const __hip_bfloat16* gp = A + (size_t)gm * K + k0 + u * 8;
            __builtin_amdgcn_global_load_lds(
                (gas_ptr)gp, (las_ptr)&As[(it * 256 + wave * 64) * 8], 16, 0, 0);
        }
        #pragma unroll
        for (int it = 0; it < 2; ++it) {
            const int idx = it * 256 + tid;
            const int r   = idx >> 3;
            const int u   = (idx & 7) ^ (r & 7);
            const __hip_bfloat16* gp = Bt + (size_t)(n0 + r) * K + k0 + u * 8;
            __builtin_amdgcn_global_load_lds(
                (gas_ptr)gp, (las_ptr)&Bs[(it * 256 + wave * 64) * 8], 16, 0, 0);
        }
        __syncthreads();

        #pragma unroll
        for (int ks = 0; ks < 2; ++ks) {
            bf16x8 af[2], bfr[2];
            #pragma unroll
            for (int mt = 0; mt < 2; ++mt) {
                const int r = wm + mt * 16 + col;
                const int u = (ks * 4 + quad) ^ (r & 7);
                af[mt] = *(const bf16x8*)(&As[r * BK + u * 8]);
            }
            #pragma unroll
            for (int nt = 0; nt < 2; ++nt) {
                const int r = wn + nt * 16 + col;
                const int u = (ks * 4 + quad) ^ (r & 7);
                bfr[nt] = *(const bf16x8*)(&Bs[r * BK + u * 8]);
            }
            #pragma unroll
            for (int mt = 0; mt < 2; ++mt)
                #pragma unroll
                for (int nt = 0; nt < 2; ++nt)
                    acc[mt][nt] = __builtin_amdgcn_mfma_f32_16x16x32_bf16(
                        af[mt], bfr[nt], acc[mt][nt], 0, 0, 0);
        }
        __syncthreads();
    }

    #pragma unroll
    for (int mt = 0; mt < 2; ++mt) {
        #pragma unroll
        for (int r = 0; r < 4; ++r) {
            const int row = m0 + wm + mt * 16 + quad * 4 + r;
            if (row >= M) continue;
            #pragma unroll
            for (int nt = 0; nt < 2; ++nt) {
                const int cg = n0 + wn + nt * 16 + col;
                C[(size_t)row * 512 + cg] = acc[mt][nt][r] + bias[cg];
            }
        }
    }
}

// ---------------------------------------------------------------------------
// Attention v3: block = 4 consecutive-x queries (one per wave). The block's
// neighborhood UNION is 55 rows (3t x 3y x 6x + bos). Stage K[55] and V[55]
// (1 KB rows) into LDS once via global_load_lds DMA; QK^T and PV then run
// entirely from LDS. Head-mix via LDS (R7-proven). LDS = 117 KB -> 1 blk/CU.
// ---------------------------------------------------------------------------
__global__ __launch_bounds__(256, 1)
void attn_v3(const float* __restrict__ Q, const __hip_bfloat16* __restrict__ KVb,
             __hip_bfloat16* __restrict__ O,
             const float* __restrict__ W_th,
             const float* __restrict__ ax1, const float* __restrict__ ax2,
             const float* __restrict__ ax3)
{
    __shared__ __align__(16) short k_lds[NUROW * 512];   // 56,320 B
    __shared__ __align__(16) short v_lds[NUROW * 512];   // 56,320 B
    __shared__ float attn_s[4][NH * NJ];                 // 3,584 B
    __shared__ float mixed_s[4][NH * NJ];                // 3,584 B

    const int tid  = threadIdx.x;
    const int wave = tid >> 6;
    const int lane = tid & 63;
    const int g    = lane >> 3;
    const int s    = lane & 7;
    const int bsw  = (blockIdx.x & 7) * (NVID / 4 / 8) + (blockIdx.x >> 3);
    const int i0   = __builtin_amdgcn_readfirstlane(bsw * 4);
    const int i    = i0 + wave;
    const int qrow = i + 1;

    const int t  = i0 / (SDIM * SDIM);
    const int rm = i0 % (SDIM * SDIM);
    const int y  = rm / SDIM;
    const int x0 = rm % SDIM;          // block's 4 queries: x0 + wave

    // ---- stage K/V union: 55 rows each, 4 rows per pass (1 per wave) ------
    #pragma unroll
    for (int p = 0; p < 14; ++p) {
        const int rs = p * 4 + wave;
        if (rs <= 54) {
            int grow;
            if (rs == 54) grow = 0;                     // bos
            else {
                const int di = rs / 18, dj = (rs / 6) % 3, dx = rs % 6;
                const int tt = t - 2 + di, yy = y - 2 + dj, xx = x0 - 2 + dx;
                grow = (tt >= 0 && yy >= 0 && xx >= 0)
                     ? 1 + tt * SDIM * SDIM + yy * SDIM + xx : 0;
            }
            __builtin_amdgcn_global_load_lds(
                (gas_ptr)(KVb + (size_t)grow * 1024 + lane * 8),
                (las_ptr)&k_lds[rs * 512], 16, 0, 0);
            __builtin_amdgcn_global_load_lds(
                (gas_ptr)(KVb + (size_t)grow * 1024 + 512 + lane * 8),
                (las_ptr)&v_lds[rs * 512], 16, 0, 0);
        }
    }

    // ---- Q + per-head constants (overlaps with DMA) -----------------------
    float qf[8];
    {
        const float4 q0 = *(const float4*)(Q + (size_t)qrow * DM + lane * 8);
        const float4 q1 = *(const float4*)(Q + (size_t)qrow * DM + lane * 8 + 4);
        qf[0] = q0.x; qf[1] = q0.y; qf[2] = q0.z; qf[3] = q0.w;
        qf[4] = q1.x; qf[5] = q1.y; qf[6] = q1.z; qf[7] = q1.w;
    }
    float a1[3], a2[3], a3[3];
    #pragma unroll
    for (int d = 0; d < 3; ++d) {
        a1[d] = ax1[d * NH + g];
        a2[d] = ax2[d * NH + g];
        a3[d] = ax3[d * NH + g];
    }

    __syncthreads();       // drains the staging DMA (vmcnt 0) + all waves

    // ---- QK^T + bias from LDS ---------------------------------------------
    float sim[NJ];
    #pragma unroll
    for (int j = 0; j < NJ; ++j) {
        int lidx; bool valid; float bias;
        if (j == 0) { lidx = 54; valid = true; bias = 0.f; }
        else {
            const int jp = j - 1;
            const int di = jp / 9, dj = (jp / 3) % 3, dk = jp % 3;
            const int tt = t + di - 2, yy = y + dj - 2, xx = x0 + wave + dk - 2;
            valid = (tt >= 0) && (yy >= 0) && (xx >= 0);
            lidx = (di * 3 + dj) * 6 + wave + dk;
            bias = a1[di] + a2[dj] + a3[dk];
        }
        if (valid) {
            const ushort8 kv = *(const ushort8*)(&k_lds[lidx * 512 + lane * 8]);
            float p = 0.f;
            #pragma unroll
            for (int e = 0; e < 8; ++e) p += bf2f(kv[e]) * qf[e];
            p += __shfl_xor(p, 1);
            p += __shfl_xor(p, 2);
            p += __shfl_xor(p, 4);
            sim[j] = p + bias;
        } else {
            sim[j] = -1e30f;
        }
    }

    // ---- softmax (per head, in registers) ---------------------------------
    float m = -1e30f;
    #pragma unroll
    for (int j = 0; j < NJ; ++j) m = fmaxf(m, sim[j]);
    float ssum = 0.f;
    #pragma unroll
    for (int j = 0; j < NJ; ++j) { sim[j] = __expf(sim[j] - m); ssum += sim[j]; }
    const float inv = 1.f / ssum;
    #pragma unroll
    for (int j = 0; j < NJ; ++j) sim[j] *= inv;

    // ---- head mix via LDS (R7-proven) -------------------------------------
    if (s == 0) {
        #pragma unroll
        for (int u = 0; u < 7; ++u) {
            f32x4 v4 = { sim[4*u], sim[4*u+1], sim[4*u+2], sim[4*u+3] };
            *(f32x4*)(&attn_s[wave][g * NJ + 4 * u]) = v4;
        }
    }
    __syncthreads();

    if (tid < NH * NJ) {
        const int h = tid / NJ, j = tid % NJ;
        #pragma unroll
        for (int q = 0; q < 4; ++q) {
            float acc = 0.f;
            #pragma unroll
            for (int gg = 0; gg < NH; ++gg)
                acc += W_th[h * NH + gg] * attn_s[q][gg * NJ + j];
            mixed_s[q][h * NJ + j] = acc;
        }
    }
    __syncthreads();

    // ---- PV from LDS ------------------------------------------------------
    float acc8[8] = {};
    #pragma unroll
    for (int j = 0; j < NJ; ++j) {
        int lidx; bool valid;
        if (j == 0) { lidx = 54; valid = true; }
        else {
            const int jp = j - 1;
            const int di = jp / 9, dj = (jp / 3) % 3, dk = jp % 3;
            const int tt = t + di - 2, yy = y + dj - 2, xx = x0 + wave + dk - 2;
            valid = (tt >= 0) && (yy >= 0) && (xx >= 0);
            lidx = (di * 3 + dj) * 6 + wave + dk;
        }
        if (valid) {
            const ushort8 vv = *(const ushort8*)(&v_lds[lidx * 512 + lane * 8]);
            const float w = mixed_s[wave][g * NJ + j];
            #pragma unroll
            for (int e = 0; e < 8; ++e) acc8[e] += w * bf2f(vv[e]);
        }
    }

    unsigned short o[8];
    #pragma unroll
    for (int e = 0; e < 8; ++e) o[e] = f2bf(acc8[e]);
    *(ushort8*)(O + (size_t)qrow * DM + lane * 8) = *(const ushort8*)o;

    if (i == 0) {
        const ushort8 vb = *(const ushort8*)(&v_lds[54 * 512 + lane * 8]);
        *(ushort8*)(O + lane * 8) = vb;
    }
}

// ---------------------------------------------------------------------------
extern "C" void kernel_launch(void* const* d_in, const int* in_sizes, int n_in,
                              void* d_out, int out_size, void* d_ws, size_t ws_size,
                              hipStream_t stream)
{
    const float* x    = (const float*)d_in[0];
    const float* Wq   = (const float*)d_in[1];
    const float* Wkv  = (const float*)d_in[2];
    const float* W_th = (const float*)d_in[3];
    const float* Wout = (const float*)d_in[4];
    const float* bout = (const float*)d_in[5];
    const float* ax1  = (const float*)d_in[6];
    const float* ax2  = (const float*)d_in[7];
    const float* ax3  = (const float*)d_in[8];
    float* out = (float*)d_out;

    char* p = (char*)d_ws;
    float* Qf = (float*)p;                       p += (size_t)NTOK * DM * 4;
    __hip_bfloat16* KVb   = (__hip_bfloat16*)p;  p += (size_t)NTOK * 2 * DM * 2;
    __hip_bfloat16* Ob    = (__hip_bfloat16*)p;  p += (size_t)NTOK * DM * 2;
    __hip_bfloat16* Wqkvt = (__hip_bfloat16*)p;  p += (size_t)3 * DM * DM * 2;
    __hip_bfloat16* Woutt = (__hip_bfloat16*)p;  p += (size_t)DM * DM * 2;
    __hip_bfloat16* xb    = (__hip_bfloat16*)p;  p += (size_t)NTOK * DM * 2;

    const dim3 blk(256);

    prep_w<<<2177, blk, 0, stream>>>(Wq, Wkv, Wout, x, Wqkvt, Woutt, xb);

    gemm_qkv<<<444, blk, 0, stream>>>(xb, Wqkvt, Qf, KVb, NTOK);

    attn_v3<<<dim3(NVID / 4), blk, 0, stream>>>(Qf, KVb, Ob, W_th, ax1, ax2, ax3);

    gemm_out<<<584, blk, 0, stream>>>(Ob, Woutt, out, NTOK, bout);
}

// Round 8
// 148.637 us; speedup vs baseline: 1.0488x; 1.0488x over previous
//
#include <hip/hip_runtime.h>
#include <hip/hip_bf16.h>

// Sparse 3DNA (causal), MI355X. Round 15 (= R14 resubmitted after GPU
// acquisition timeout; kernel never executed).
// GEMMs/prep = R1-proven (131us) config, untouched. attn_v4: back to
// one-wave-per-query direct gathers (no KV LDS), but with EXPLICIT 7-deep
// load batching (issue 7 independent gathers -> one drain -> 7 dots) so
// exposed latency waits per phase drop 28 -> 4, and __launch_bounds__(256,4)
// for 4 blocks/CU residency (16 waves/CU TLP). Theory from R6 counters:
// attn is latency-serialized (per-wave ~12us = 56 loads x ~500cy, compiler
// recycles VGPRs after each gather) with ~1 block/CU residency.

constexpr int TFR   = 8;
constexpr int SDIM  = 24;
constexpr int NVID  = TFR * SDIM * SDIM;   // 4608
constexpr int NTOK  = NVID + 1;            // 4609
constexpr int NH    = 8;
constexpr int DM    = 512;
constexpr int NJ    = 28;

typedef __attribute__((ext_vector_type(8))) short bf16x8;
typedef __attribute__((ext_vector_type(8))) unsigned short ushort8;
typedef __attribute__((ext_vector_type(4))) float f32x4;

typedef const __attribute__((address_space(1))) unsigned int* gas_ptr;
typedef __attribute__((address_space(3))) unsigned int* las_ptr;

__device__ __forceinline__ float bf2f(unsigned short u) {
    return __uint_as_float((unsigned)u << 16);
}
__device__ __forceinline__ unsigned short f2bf(float f) {
    __hip_bfloat16 h = __float2bfloat16(f);
    return reinterpret_cast<unsigned short&>(h);
}

// ---------------------------------------------------------------------------
// prep: transpose+cast Wq/Wkv and Wout; straight cast x -> xb (bf16).
// ---------------------------------------------------------------------------
__global__ __launch_bounds__(256)
void prep_w(const float* __restrict__ Wq, const float* __restrict__ Wkv,
            const float* __restrict__ Wout, const float* __restrict__ x,
            __hip_bfloat16* __restrict__ Wqkvt, __hip_bfloat16* __restrict__ Woutt,
            __hip_bfloat16* __restrict__ xb)
{
    const int tid = threadIdx.x;
    int tb = blockIdx.x;

    if (tb >= 1024) {                       // ---- x cast: fp32 -> bf16 ----
        const size_t base = (size_t)(tb - 1024) * 2048 + (size_t)tid * 8;
        if (base < (size_t)NTOK * DM) {
            const float4 f0 = *(const float4*)(x + base);
            const float4 f1 = *(const float4*)(x + base + 4);
            unsigned short v[8] = { f2bf(f0.x), f2bf(f0.y), f2bf(f0.z), f2bf(f0.w),
                                    f2bf(f1.x), f2bf(f1.y), f2bf(f1.z), f2bf(f1.w) };
            *(ushort8*)(xb + base) = *(const ushort8*)v;
        }
        return;
    }

    __shared__ float t[32][33];
    const float* W; __hip_bfloat16* Wt; int Nd, tX, rowOff;
    if (tb < 256)      { W = Wq;   Wt = Wqkvt; Nd = 512;  tX = 16; rowOff = 0;   }
    else if (tb < 768) { tb -= 256; W = Wkv;  Wt = Wqkvt; Nd = 1024; tX = 32; rowOff = 512; }
    else               { tb -= 768; W = Wout; Wt = Woutt; Nd = 512;  tX = 16; rowOff = 0;   }
    const int n0 = (tb % tX) * 32, k0 = (tb / tX) * 32;
    const int r  = tid >> 3;
    const int c4 = (tid & 7) * 4;
    const float4 v = *(const float4*)(W + (size_t)(k0 + r) * Nd + n0 + c4);
    t[r][c4 + 0] = v.x; t[r][c4 + 1] = v.y; t[r][c4 + 2] = v.z; t[r][c4 + 3] = v.w;
    __syncthreads();
    #pragma unroll
    for (int j = 0; j < 4; ++j)
        Wt[(size_t)(rowOff + n0 + r) * 512 + k0 + c4 + j] = __float2bfloat16(t[c4 + j][r]);
}

// ---------------------------------------------------------------------------
// QKV GEMM (R1-proven): BM=BN=128, BK=64, 444 blocks, XCD-chunked, both
// operands global_load_lds + XOR swizzle.
// ---------------------------------------------------------------------------
__global__ __launch_bounds__(256)
void gemm_qkv(const __hip_bfloat16* __restrict__ Ab, const __hip_bfloat16* __restrict__ Bt,
              float* __restrict__ Cq, __hip_bfloat16* __restrict__ Ckv, int M)
{
    constexpr int BM = 128, BN = 128, BK = 64, K = 512;
    __shared__ __align__(16) short As[BM * BK];
    __shared__ __align__(16) short Bs[BN * BK];

    const int tid  = threadIdx.x;
    const int bid  = blockIdx.x;
    const int xcd  = bid & 7, pos = bid >> 3;
    const int L    = (xcd < 4) ? xcd * 56 + pos : 224 + (xcd - 4) * 55 + pos;
    const int m0   = (L / 12) * BM;
    const int n0   = (L % 12) * BN;

    const int lane = tid & 63;
    const int wave = tid >> 6;
    const int wm   = (wave >> 1) * 64;
    const int wn   = (wave & 1) * 64;
    const int col  = lane & 15;
    const int quad = lane >> 4;

    f32x4 acc[4][4] = {};

    for (int k0 = 0; k0 < K; k0 += BK) {
        #pragma unroll
        for (int it = 0; it < 4; ++it) {
            const int idx = it * 256 + tid;
            const int r   = idx >> 3;
            const int u   = (idx & 7) ^ (r & 7);
            const int gm  = (m0 + r < M) ? (m0 + r) : (M - 1);
            const __hip_bfloat16* gp = Ab + (size_t)gm * K + k0 + u * 8;
            __builtin_amdgcn_global_load_lds(
                (gas_ptr)gp, (las_ptr)&As[(it * 256 + wave * 64) * 8], 16, 0, 0);
        }
        #pragma unroll
        for (int it = 0; it < 4; ++it) {
            const int idx = it * 256 + tid;
            const int r   = idx >> 3;
            const int u   = (idx & 7) ^ (r & 7);
            const __hip_bfloat16* gp = Bt + (size_t)(n0 + r) * K + k0 + u * 8;
            __builtin_amdgcn_global_load_lds(
                (gas_ptr)gp, (las_ptr)&Bs[(it * 256 + wave * 64) * 8], 16, 0, 0);
        }
        __syncthreads();

        #pragma unroll
        for (int ks = 0; ks < 2; ++ks) {
            bf16x8 af[4], bfr[4];
            #pragma unroll
            for (int mt = 0; mt < 4; ++mt) {
                const int r = wm + mt * 16 + col;
                const int u = (ks * 4 + quad) ^ (r & 7);
                af[mt] = *(const bf16x8*)(&As[r * BK + u * 8]);
            }
            #pragma unroll
            for (int nt = 0; nt < 4; ++nt) {
                const int r = wn + nt * 16 + col;
                const int u = (ks * 4 + quad) ^ (r & 7);
                bfr[nt] = *(const bf16x8*)(&Bs[r * BK + u * 8]);
            }
            #pragma unroll
            for (int mt = 0; mt < 4; ++mt)
                #pragma unroll
                for (int nt = 0; nt < 4; ++nt)
                    acc[mt][nt] = __builtin_amdgcn_mfma_f32_16x16x32_bf16(
                        af[mt], bfr[nt], acc[mt][nt], 0, 0, 0);
        }
        __syncthreads();
    }

    const bool isQ = (n0 < 512);
    #pragma unroll
    for (int mt = 0; mt < 4; ++mt) {
        #pragma unroll
        for (int r = 0; r < 4; ++r) {
            const int row = m0 + wm + mt * 16 + quad * 4 + r;
            if (row >= M) continue;
            #pragma unroll
            for (int nt = 0; nt < 4; ++nt) {
                const int cg = n0 + wn + nt * 16 + col;
                const float v = acc[mt][nt][r];
                if (isQ) Cq[(size_t)row * 512 + cg] = v * 0.125f;
                else     Ckv[(size_t)row * 1024 + (cg - 512)] = __float2bfloat16(v);
            }
        }
    }
}

// ---------------------------------------------------------------------------
// out-proj GEMM (R1-proven): BM=BN=64, 584 blocks, XCD-chunked.
// ---------------------------------------------------------------------------
__global__ __launch_bounds__(256)
void gemm_out(const __hip_bfloat16* __restrict__ A, const __hip_bfloat16* __restrict__ Bt,
              float* __restrict__ C, int M, const float* __restrict__ bias)
{
    constexpr int BM = 64, BN = 64, BK = 64, K = 512;
    __shared__ __align__(16) short As[BM * BK];
    __shared__ __align__(16) short Bs[BN * BK];

    const int tid  = threadIdx.x;
    const int bid  = blockIdx.x;
    const int L    = (bid & 7) * 73 + (bid >> 3);   // 584 = 8*73 exact
    const int m0   = (L >> 3) * BM;
    const int n0   = (L & 7) * BN;
    const int lane = tid & 63;
    const int wave = tid >> 6;
    const int wm   = (wave >> 1) * 32;
    const int wn   = (wave & 1) * 32;
    const int col  = lane & 15;
    const int quad = lane >> 4;

    f32x4 acc[2][2] = {};

    for (int k0 = 0; k0 < K; k0 += BK) {
        #pragma unroll
        for (int it = 0; it < 2; ++it) {
            const int idx = it * 256 + tid;
            const int r   = idx >> 3;
            const int u   = (idx & 7) ^ (r & 7);
            const int gm  = (m0 + r < M) ? (m0 + r) : (M - 1);
            const __hip_bfloat16* gp = A + (size_t)gm * K + k0 + u * 8;
            __builtin_amdgcn_global_load_lds(
                (gas_ptr)gp, (las_ptr)&As[(it * 256 + wave * 64) * 8], 16, 0, 0);
        }
        #pragma unroll
        for (int it = 0; it < 2; ++it) {
            const int idx = it * 256 + tid;
            const int r   = idx >> 3;
            const int u   = (idx & 7) ^ (r & 7);
            const __hip_bfloat16* gp = Bt + (size_t)(n0 + r) * K + k0 + u * 8;
            __builtin_amdgcn_global_load_lds(
                (gas_ptr)gp, (las_ptr)&Bs[(it * 256 + wave * 64) * 8], 16, 0, 0);
        }
        __syncthreads();

        #pragma unroll
        for (int ks = 0; ks < 2; ++ks) {
            bf16x8 af[2], bfr[2];
            #pragma unroll
            for (int mt = 0; mt < 2; ++mt) {
                const int r = wm + mt * 16 + col;
                const int u = (ks * 4 + quad) ^ (r & 7);
                af[mt] = *(const bf16x8*)(&As[r * BK + u * 8]);
            }
            #pragma unroll
            for (int nt = 0; nt < 2; ++nt) {
                const int r = wn + nt * 16 + col;
                const int u = (ks * 4 + quad) ^ (r & 7);
                bfr[nt] = *(const bf16x8*)(&Bs[r * BK + u * 8]);
            }
            #pragma unroll
            for (int mt = 0; mt < 2; ++mt)
                #pragma unroll
                for (int nt = 0; nt < 2; ++nt)
                    acc[mt][nt] = __builtin_amdgcn_mfma_f32_16x16x32_bf16(
                        af[mt], bfr[nt], acc[mt][nt], 0, 0, 0);
        }
        __syncthreads();
    }

    #pragma unroll
    for (int mt = 0; mt < 2; ++mt) {
        #pragma unroll
        for (int r = 0; r < 4; ++r) {
            const int row = m0 + wm + mt * 16 + quad * 4 + r;
            if (row >= M) continue;
            #pragma unroll
            for (int nt = 0; nt < 2; ++nt) {
                const int cg = n0 + wn + nt * 16 + col;
                C[(size_t)row * 512 + cg] = acc[mt][nt][r] + bias[cg];
            }
        }
    }
}

// ---------------------------------------------------------------------------
// Attention v4: one wave per query, 4 queries/block, direct gathers with
// 7-deep explicit load batching in both phases. Branch-free batch bodies
// (invalid neighbors load row 0, masked at sim write; validity is
// wave-uniform). Head-mix via small LDS (R1-proven). 4 blocks/CU target.
// ---------------------------------------------------------------------------
__global__ __launch_bounds__(256, 4)
void attn_v4(const float* __restrict__ Q, const __hip_bfloat16* __restrict__ KVb,
             __hip_bfloat16* __restrict__ O,
             const float* __restrict__ W_th,
             const float* __restrict__ ax1, const float* __restrict__ ax2,
             const float* __restrict__ ax3)
{
    __shared__ float attn_s[4][NH * NJ];
    __shared__ float mixed_s[4][NH * NJ];

    const int tid  = threadIdx.x;
    const int wave = tid >> 6;
    const int lane = tid & 63;
    const int g    = lane >> 3;
    const int s    = lane & 7;
    const int bsw  = (blockIdx.x & 7) * (NVID / 4 / 8) + (blockIdx.x >> 3);
    const int i    = __builtin_amdgcn_readfirstlane(bsw * 4 + wave);
    const int qrow = i + 1;

    const int t  = i / (SDIM * SDIM);
    const int rm = i % (SDIM * SDIM);
    const int y  = rm / SDIM;
    const int x  = rm % SDIM;

    float qf[8];
    {
        const float4 q0 = *(const float4*)(Q + (size_t)qrow * DM + lane * 8);
        const float4 q1 = *(const float4*)(Q + (size_t)qrow * DM + lane * 8 + 4);
        qf[0] = q0.x; qf[1] = q0.y; qf[2] = q0.z; qf[3] = q0.w;
        qf[4] = q1.x; qf[5] = q1.y; qf[6] = q1.z; qf[7] = q1.w;
    }
    float a1[3], a2[3], a3[3];
    #pragma unroll
    for (int d = 0; d < 3; ++d) {
        a1[d] = ax1[d * NH + g];
        a2[d] = ax2[d * NH + g];
        a3[d] = ax3[d * NH + g];
    }

    // ---- Phase 1: QK^T, 4 batches of 7 gathers ----------------------------
    float sim[NJ];
    #pragma unroll
    for (int b = 0; b < 4; ++b) {
        ushort8 kb[7];
        #pragma unroll
        for (int u = 0; u < 7; ++u) {
            const int j = b * 7 + u;
            int row = 0;
            if (j != 0) {
                const int jp = j - 1;
                const int di = jp / 9, dj = (jp / 3) % 3, dk = jp % 3;
                const int tt = t + di - 2, yy = y + dj - 2, xx = x + dk - 2;
                row = (tt >= 0 && yy >= 0 && xx >= 0)
                    ? 1 + tt * SDIM * SDIM + yy * SDIM + xx : 0;
            }
            kb[u] = *(const ushort8*)(KVb + (size_t)row * 1024 + lane * 8);
        }
        #pragma unroll
        for (int u = 0; u < 7; ++u) {
            const int j = b * 7 + u;
            float p = 0.f;
            #pragma unroll
            for (int e = 0; e < 8; ++e) p += bf2f(kb[u][e]) * qf[e];
            p += __shfl_xor(p, 1);
            p += __shfl_xor(p, 2);
            p += __shfl_xor(p, 4);
            if (j == 0) {
                sim[j] = p;
            } else {
                const int jp = j - 1;
                const int di = jp / 9, dj = (jp / 3) % 3, dk = jp % 3;
                const int tt = t + di - 2, yy = y + dj - 2, xx = x + dk - 2;
                const bool valid = (tt >= 0) && (yy >= 0) && (xx >= 0);
                sim[j] = valid ? (p + a1[di] + a2[dj] + a3[dk]) : -1e30f;
            }
        }
    }

    // ---- softmax (per head, in registers) ---------------------------------
    float m = -1e30f;
    #pragma unroll
    for (int j = 0; j < NJ; ++j) m = fmaxf(m, sim[j]);
    float ssum = 0.f;
    #pragma unroll
    for (int j = 0; j < NJ; ++j) { sim[j] = __expf(sim[j] - m); ssum += sim[j]; }
    const float inv = 1.f / ssum;
    #pragma unroll
    for (int j = 0; j < NJ; ++j) sim[j] *= inv;

    // ---- head mix via LDS (R1-proven) -------------------------------------
    if (s == 0) {
        #pragma unroll
        for (int u = 0; u < 7; ++u) {
            f32x4 v4 = { sim[4*u], sim[4*u+1], sim[4*u+2], sim[4*u+3] };
            *(f32x4*)(&attn_s[wave][g * NJ + 4 * u]) = v4;
        }
    }
    __syncthreads();

    if (tid < NH * NJ) {
        const int h = tid / NJ, j = tid % NJ;
        #pragma unroll
        for (int q = 0; q < 4; ++q) {
            float acc = 0.f;
            #pragma unroll
            for (int gg = 0; gg < NH; ++gg)
                acc += W_th[h * NH + gg] * attn_s[q][gg * NJ + j];
            mixed_s[q][h * NJ + j] = acc;
        }
    }
    __syncthreads();

    // ---- Phase 2: PV, 4 batches of 7 gathers ------------------------------
    float acc8[8] = {};
    #pragma unroll
    for (int b = 0; b < 4; ++b) {
        ushort8 vb[7];
        #pragma unroll
        for (int u = 0; u < 7; ++u) {
            const int j = b * 7 + u;
            int row = 0;
            if (j != 0) {
                const int jp = j - 1;
                const int di = jp / 9, dj = (jp / 3) % 3, dk = jp % 3;
                const int tt = t + di - 2, yy = y + dj - 2, xx = x + dk - 2;
                row = (tt >= 0 && yy >= 0 && xx >= 0)
                    ? 1 + tt * SDIM * SDIM + yy * SDIM + xx : 0;
            }
            vb[u] = *(const ushort8*)(KVb + (size_t)row * 1024 + 512 + lane * 8);
        }
        #pragma unroll
        for (int u = 0; u < 7; ++u) {
            const int j = b * 7 + u;
            bool valid = true;
            if (j != 0) {
                const int jp = j - 1;
                const int di = jp / 9, dj = (jp / 3) % 3, dk = jp % 3;
                valid = (t + di - 2 >= 0) && (y + dj - 2 >= 0) && (x + dk - 2 >= 0);
            }
            const float w = valid ? mixed_s[wave][g * NJ + j] : 0.f;
            #pragma unroll
            for (int e = 0; e < 8; ++e) acc8[e] += w * bf2f(vb[u][e]);
        }
    }

    unsigned short o[8];
    #pragma unroll
    for (int e = 0; e < 8; ++e) o[e] = f2bf(acc8[e]);
    *(ushort8*)(O + (size_t)qrow * DM + lane * 8) = *(const ushort8*)o;

    if (i == 0) {
        const ushort8 vb0 = *(const ushort8*)(KVb + 512 + lane * 8);
        *(ushort8*)(O + lane * 8) = vb0;
    }
}

// ---------------------------------------------------------------------------
extern "C" void kernel_launch(void* const* d_in, const int* in_sizes, int n_in,
                              void* d_out, int out_size, void* d_ws, size_t ws_size,
                              hipStream_t stream)
{
    const float* x    = (const float*)d_in[0];
    const float* Wq   = (const float*)d_in[1];
    const float* Wkv  = (const float*)d_in[2];
    const float* W_th = (const float*)d_in[3];
    const float* Wout = (const float*)d_in[4];
    const float* bout = (const float*)d_in[5];
    const float* ax1  = (const float*)d_in[6];
    const float* ax2  = (const float*)d_in[7];
    const float* ax3  = (const float*)d_in[8];
    float* out = (float*)d_out;

    char* p = (char*)d_ws;
    float* Qf = (float*)p;                       p += (size_t)NTOK * DM * 4;
    __hip_bfloat16* KVb   = (__hip_bfloat16*)p;  p += (size_t)NTOK * 2 * DM * 2;
    __hip_bfloat16* Ob    = (__hip_bfloat16*)p;  p += (size_t)NTOK * DM * 2;
    __hip_bfloat16* Wqkvt = (__hip_bfloat16*)p;  p += (size_t)3 * DM * DM * 2;
    __hip_bfloat16* Woutt = (__hip_bfloat16*)p;  p += (size_t)DM * DM * 2;
    __hip_bfloat16* xb    = (__hip_bfloat16*)p;  p += (size_t)NTOK * DM * 2;

    const dim3 blk(256);

    prep_w<<<2177, blk, 0, stream>>>(Wq, Wkv, Wout, x, Wqkvt, Woutt, xb);

    gemm_qkv<<<444, blk, 0, stream>>>(xb, Wqkvt, Qf, KVb, NTOK);

    attn_v4<<<dim3(NVID / 4), blk, 0, stream>>>(Qf, KVb, Ob, W_th, ax1, ax2, ax3);

    gemm_out<<<584, blk, 0, stream>>>(Ob, Woutt, out, NTOK, bout);
}

// Round 9
// 127.960 us; speedup vs baseline: 1.2183x; 1.1616x over previous
//
#include <hip/hip_runtime.h>
#include <hip/hip_bf16.h>

// Sparse 3DNA (causal), MI355X. Round 16:
// R15 base. Single change: attn __launch_bounds__(256,4) -> (256,3).
// R8 counters showed (256,4) forced VGPR_Count=64 -> massive scratch spill
// (WRITE_SIZE 64.5MB vs 4.6MB of real output; FETCH +30MB) and capped
// residency at ~2 blocks/CU anyway. Need ~120 VGPRs (sim[28]+kb[7]+qf[8]);
// (256,3) caps at 170 VGPRs = no spill, 12 waves/CU TLP.

constexpr int TFR   = 8;
constexpr int SDIM  = 24;
constexpr int NVID  = TFR * SDIM * SDIM;   // 4608
constexpr int NTOK  = NVID + 1;            // 4609
constexpr int NH    = 8;
constexpr int DM    = 512;
constexpr int NJ    = 28;

typedef __attribute__((ext_vector_type(8))) short bf16x8;
typedef __attribute__((ext_vector_type(8))) unsigned short ushort8;
typedef __attribute__((ext_vector_type(4))) float f32x4;

typedef const __attribute__((address_space(1))) unsigned int* gas_ptr;
typedef __attribute__((address_space(3))) unsigned int* las_ptr;

__device__ __forceinline__ float bf2f(unsigned short u) {
    return __uint_as_float((unsigned)u << 16);
}
__device__ __forceinline__ unsigned short f2bf(float f) {
    __hip_bfloat16 h = __float2bfloat16(f);
    return reinterpret_cast<unsigned short&>(h);
}

// ---------------------------------------------------------------------------
// prep: transpose+cast Wq/Wkv and Wout; straight cast x -> xb (bf16).
// ---------------------------------------------------------------------------
__global__ __launch_bounds__(256)
void prep_w(const float* __restrict__ Wq, const float* __restrict__ Wkv,
            const float* __restrict__ Wout, const float* __restrict__ x,
            __hip_bfloat16* __restrict__ Wqkvt, __hip_bfloat16* __restrict__ Woutt,
            __hip_bfloat16* __restrict__ xb)
{
    const int tid = threadIdx.x;
    int tb = blockIdx.x;

    if (tb >= 1024) {                       // ---- x cast: fp32 -> bf16 ----
        const size_t base = (size_t)(tb - 1024) * 2048 + (size_t)tid * 8;
        if (base < (size_t)NTOK * DM) {
            const float4 f0 = *(const float4*)(x + base);
            const float4 f1 = *(const float4*)(x + base + 4);
            unsigned short v[8] = { f2bf(f0.x), f2bf(f0.y), f2bf(f0.z), f2bf(f0.w),
                                    f2bf(f1.x), f2bf(f1.y), f2bf(f1.z), f2bf(f1.w) };
            *(ushort8*)(xb + base) = *(const ushort8*)v;
        }
        return;
    }

    __shared__ float t[32][33];
    const float* W; __hip_bfloat16* Wt; int Nd, tX, rowOff;
    if (tb < 256)      { W = Wq;   Wt = Wqkvt; Nd = 512;  tX = 16; rowOff = 0;   }
    else if (tb < 768) { tb -= 256; W = Wkv;  Wt = Wqkvt; Nd = 1024; tX = 32; rowOff = 512; }
    else               { tb -= 768; W = Wout; Wt = Woutt; Nd = 512;  tX = 16; rowOff = 0;   }
    const int n0 = (tb % tX) * 32, k0 = (tb / tX) * 32;
    const int r  = tid >> 3;
    const int c4 = (tid & 7) * 4;
    const float4 v = *(const float4*)(W + (size_t)(k0 + r) * Nd + n0 + c4);
    t[r][c4 + 0] = v.x; t[r][c4 + 1] = v.y; t[r][c4 + 2] = v.z; t[r][c4 + 3] = v.w;
    __syncthreads();
    #pragma unroll
    for (int j = 0; j < 4; ++j)
        Wt[(size_t)(rowOff + n0 + r) * 512 + k0 + c4 + j] = __float2bfloat16(t[c4 + j][r]);
}

// ---------------------------------------------------------------------------
// QKV GEMM (R1-proven): BM=BN=128, BK=64, 444 blocks, XCD-chunked, both
// operands global_load_lds + XOR swizzle.
// ---------------------------------------------------------------------------
__global__ __launch_bounds__(256)
void gemm_qkv(const __hip_bfloat16* __restrict__ Ab, const __hip_bfloat16* __restrict__ Bt,
              float* __restrict__ Cq, __hip_bfloat16* __restrict__ Ckv, int M)
{
    constexpr int BM = 128, BN = 128, BK = 64, K = 512;
    __shared__ __align__(16) short As[BM * BK];
    __shared__ __align__(16) short Bs[BN * BK];

    const int tid  = threadIdx.x;
    const int bid  = blockIdx.x;
    const int xcd  = bid & 7, pos = bid >> 3;
    const int L    = (xcd < 4) ? xcd * 56 + pos : 224 + (xcd - 4) * 55 + pos;
    const int m0   = (L / 12) * BM;
    const int n0   = (L % 12) * BN;

    const int lane = tid & 63;
    const int wave = tid >> 6;
    const int wm   = (wave >> 1) * 64;
    const int wn   = (wave & 1) * 64;
    const int col  = lane & 15;
    const int quad = lane >> 4;

    f32x4 acc[4][4] = {};

    for (int k0 = 0; k0 < K; k0 += BK) {
        #pragma unroll
        for (int it = 0; it < 4; ++it) {
            const int idx = it * 256 + tid;
            const int r   = idx >> 3;
            const int u   = (idx & 7) ^ (r & 7);
            const int gm  = (m0 + r < M) ? (m0 + r) : (M - 1);
            const __hip_bfloat16* gp = Ab + (size_t)gm * K + k0 + u * 8;
            __builtin_amdgcn_global_load_lds(
                (gas_ptr)gp, (las_ptr)&As[(it * 256 + wave * 64) * 8], 16, 0, 0);
        }
        #pragma unroll
        for (int it = 0; it < 4; ++it) {
            const int idx = it * 256 + tid;
            const int r   = idx >> 3;
            const int u   = (idx & 7) ^ (r & 7);
            const __hip_bfloat16* gp = Bt + (size_t)(n0 + r) * K + k0 + u * 8;
            __builtin_amdgcn_global_load_lds(
                (gas_ptr)gp, (las_ptr)&Bs[(it * 256 + wave * 64) * 8], 16, 0, 0);
        }
        __syncthreads();

        #pragma unroll
        for (int ks = 0; ks < 2; ++ks) {
            bf16x8 af[4], bfr[4];
            #pragma unroll
            for (int mt = 0; mt < 4; ++mt) {
                const int r = wm + mt * 16 + col;
                const int u = (ks * 4 + quad) ^ (r & 7);
                af[mt] = *(const bf16x8*)(&As[r * BK + u * 8]);
            }
            #pragma unroll
            for (int nt = 0; nt < 4; ++nt) {
                const int r = wn + nt * 16 + col;
                const int u = (ks * 4 + quad) ^ (r & 7);
                bfr[nt] = *(const bf16x8*)(&Bs[r * BK + u * 8]);
            }
            #pragma unroll
            for (int mt = 0; mt < 4; ++mt)
                #pragma unroll
                for (int nt = 0; nt < 4; ++nt)
                    acc[mt][nt] = __builtin_amdgcn_mfma_f32_16x16x32_bf16(
                        af[mt], bfr[nt], acc[mt][nt], 0, 0, 0);
        }
        __syncthreads();
    }

    const bool isQ = (n0 < 512);
    #pragma unroll
    for (int mt = 0; mt < 4; ++mt) {
        #pragma unroll
        for (int r = 0; r < 4; ++r) {
            const int row = m0 + wm + mt * 16 + quad * 4 + r;
            if (row >= M) continue;
            #pragma unroll
            for (int nt = 0; nt < 4; ++nt) {
                const int cg = n0 + wn + nt * 16 + col;
                const float v = acc[mt][nt][r];
                if (isQ) Cq[(size_t)row * 512 + cg] = v * 0.125f;
                else     Ckv[(size_t)row * 1024 + (cg - 512)] = __float2bfloat16(v);
            }
        }
    }
}

// ---------------------------------------------------------------------------
// out-proj GEMM (R1-proven): BM=BN=64, 584 blocks, XCD-chunked.
// ---------------------------------------------------------------------------
__global__ __launch_bounds__(256)
void gemm_out(const __hip_bfloat16* __restrict__ A, const __hip_bfloat16* __restrict__ Bt,
              float* __restrict__ C, int M, const float* __restrict__ bias)
{
    constexpr int BM = 64, BN = 64, BK = 64, K = 512;
    __shared__ __align__(16) short As[BM * BK];
    __shared__ __align__(16) short Bs[BN * BK];

    const int tid  = threadIdx.x;
    const int bid  = blockIdx.x;
    const int L    = (bid & 7) * 73 + (bid >> 3);   // 584 = 8*73 exact
    const int m0   = (L >> 3) * BM;
    const int n0   = (L & 7) * BN;
    const int lane = tid & 63;
    const int wave = tid >> 6;
    const int wm   = (wave >> 1) * 32;
    const int wn   = (wave & 1) * 32;
    const int col  = lane & 15;
    const int quad = lane >> 4;

    f32x4 acc[2][2] = {};

    for (int k0 = 0; k0 < K; k0 += BK) {
        #pragma unroll
        for (int it = 0; it < 2; ++it) {
            const int idx = it * 256 + tid;
            const int r   = idx >> 3;
            const int u   = (idx & 7) ^ (r & 7);
            const int gm  = (m0 + r < M) ? (m0 + r) : (M - 1);
            const __hip_bfloat16* gp = A + (size_t)gm * K + k0 + u * 8;
            __builtin_amdgcn_global_load_lds(
                (gas_ptr)gp, (las_ptr)&As[(it * 256 + wave * 64) * 8], 16, 0, 0);
        }
        #pragma unroll
        for (int it = 0; it < 2; ++it) {
            const int idx = it * 256 + tid;
            const int r   = idx >> 3;
            const int u   = (idx & 7) ^ (r & 7);
            const __hip_bfloat16* gp = Bt + (size_t)(n0 + r) * K + k0 + u * 8;
            __builtin_amdgcn_global_load_lds(
                (gas_ptr)gp, (las_ptr)&Bs[(it * 256 + wave * 64) * 8], 16, 0, 0);
        }
        __syncthreads();

        #pragma unroll
        for (int ks = 0; ks < 2; ++ks) {
            bf16x8 af[2], bfr[2];
            #pragma unroll
            for (int mt = 0; mt < 2; ++mt) {
                const int r = wm + mt * 16 + col;
                const int u = (ks * 4 + quad) ^ (r & 7);
                af[mt] = *(const bf16x8*)(&As[r * BK + u * 8]);
            }
            #pragma unroll
            for (int nt = 0; nt < 2; ++nt) {
                const int r = wn + nt * 16 + col;
                const int u = (ks * 4 + quad) ^ (r & 7);
                bfr[nt] = *(const bf16x8*)(&Bs[r * BK + u * 8]);
            }
            #pragma unroll
            for (int mt = 0; mt < 2; ++mt)
                #pragma unroll
                for (int nt = 0; nt < 2; ++nt)
                    acc[mt][nt] = __builtin_amdgcn_mfma_f32_16x16x32_bf16(
                        af[mt], bfr[nt], acc[mt][nt], 0, 0, 0);
        }
        __syncthreads();
    }

    #pragma unroll
    for (int mt = 0; mt < 2; ++mt) {
        #pragma unroll
        for (int r = 0; r < 4; ++r) {
            const int row = m0 + wm + mt * 16 + quad * 4 + r;
            if (row >= M) continue;
            #pragma unroll
            for (int nt = 0; nt < 2; ++nt) {
                const int cg = n0 + wn + nt * 16 + col;
                C[(size_t)row * 512 + cg] = acc[mt][nt][r] + bias[cg];
            }
        }
    }
}

// ---------------------------------------------------------------------------
// Attention v4b: one wave per query, 4 queries/block, direct gathers with
// 7-deep explicit load batching in both phases. __launch_bounds__(256,3):
// 170-VGPR cap fits the ~120-VGPR live set (no scratch), 12 waves/CU.
// ---------------------------------------------------------------------------
__global__ __launch_bounds__(256, 3)
void attn_v4(const float* __restrict__ Q, const __hip_bfloat16* __restrict__ KVb,
             __hip_bfloat16* __restrict__ O,
             const float* __restrict__ W_th,
             const float* __restrict__ ax1, const float* __restrict__ ax2,
             const float* __restrict__ ax3)
{
    __shared__ float attn_s[4][NH * NJ];
    __shared__ float mixed_s[4][NH * NJ];

    const int tid  = threadIdx.x;
    const int wave = tid >> 6;
    const int lane = tid & 63;
    const int g    = lane >> 3;
    const int s    = lane & 7;
    const int bsw  = (blockIdx.x & 7) * (NVID / 4 / 8) + (blockIdx.x >> 3);
    const int i    = __builtin_amdgcn_readfirstlane(bsw * 4 + wave);
    const int qrow = i + 1;

    const int t  = i / (SDIM * SDIM);
    const int rm = i % (SDIM * SDIM);
    const int y  = rm / SDIM;
    const int x  = rm % SDIM;

    float qf[8];
    {
        const float4 q0 = *(const float4*)(Q + (size_t)qrow * DM + lane * 8);
        const float4 q1 = *(const float4*)(Q + (size_t)qrow * DM + lane * 8 + 4);
        qf[0] = q0.x; qf[1] = q0.y; qf[2] = q0.z; qf[3] = q0.w;
        qf[4] = q1.x; qf[5] = q1.y; qf[6] = q1.z; qf[7] = q1.w;
    }
    float a1[3], a2[3], a3[3];
    #pragma unroll
    for (int d = 0; d < 3; ++d) {
        a1[d] = ax1[d * NH + g];
        a2[d] = ax2[d * NH + g];
        a3[d] = ax3[d * NH + g];
    }

    // ---- Phase 1: QK^T, 4 batches of 7 gathers ----------------------------
    float sim[NJ];
    #pragma unroll
    for (int b = 0; b < 4; ++b) {
        ushort8 kb[7];
        #pragma unroll
        for (int u = 0; u < 7; ++u) {
            const int j = b * 7 + u;
            int row = 0;
            if (j != 0) {
                const int jp = j - 1;
                const int di = jp / 9, dj = (jp / 3) % 3, dk = jp % 3;
                const int tt = t + di - 2, yy = y + dj - 2, xx = x + dk - 2;
                row = (tt >= 0 && yy >= 0 && xx >= 0)
                    ? 1 + tt * SDIM * SDIM + yy * SDIM + xx : 0;
            }
            kb[u] = *(const ushort8*)(KVb + (size_t)row * 1024 + lane * 8);
        }
        #pragma unroll
        for (int u = 0; u < 7; ++u) {
            const int j = b * 7 + u;
            float p = 0.f;
            #pragma unroll
            for (int e = 0; e < 8; ++e) p += bf2f(kb[u][e]) * qf[e];
            p += __shfl_xor(p, 1);
            p += __shfl_xor(p, 2);
            p += __shfl_xor(p, 4);
            if (j == 0) {
                sim[j] = p;
            } else {
                const int jp = j - 1;
                const int di = jp / 9, dj = (jp / 3) % 3, dk = jp % 3;
                const int tt = t + di - 2, yy = y + dj - 2, xx = x + dk - 2;
                const bool valid = (tt >= 0) && (yy >= 0) && (xx >= 0);
                sim[j] = valid ? (p + a1[di] + a2[dj] + a3[dk]) : -1e30f;
            }
        }
    }

    // ---- softmax (per head, in registers) ---------------------------------
    float m = -1e30f;
    #pragma unroll
    for (int j = 0; j < NJ; ++j) m = fmaxf(m, sim[j]);
    float ssum = 0.f;
    #pragma unroll
    for (int j = 0; j < NJ; ++j) { sim[j] = __expf(sim[j] - m); ssum += sim[j]; }
    const float inv = 1.f / ssum;
    #pragma unroll
    for (int j = 0; j < NJ; ++j) sim[j] *= inv;

    // ---- head mix via LDS (R1-proven) -------------------------------------
    if (s == 0) {
        #pragma unroll
        for (int u = 0; u < 7; ++u) {
            f32x4 v4 = { sim[4*u], sim[4*u+1], sim[4*u+2], sim[4*u+3] };
            *(f32x4*)(&attn_s[wave][g * NJ + 4 * u]) = v4;
        }
    }
    __syncthreads();

    if (tid < NH * NJ) {
        const int h = tid / NJ, j = tid % NJ;
        #pragma unroll
        for (int q = 0; q < 4; ++q) {
            float acc = 0.f;
            #pragma unroll
            for (int gg = 0; gg < NH; ++gg)
                acc += W_th[h * NH + gg] * attn_s[q][gg * NJ + j];
            mixed_s[q][h * NJ + j] = acc;
        }
    }
    __syncthreads();

    // ---- Phase 2: PV, 4 batches of 7 gathers ------------------------------
    float acc8[8] = {};
    #pragma unroll
    for (int b = 0; b < 4; ++b) {
        ushort8 vb[7];
        #pragma unroll
        for (int u = 0; u < 7; ++u) {
            const int j = b * 7 + u;
            int row = 0;
            if (j != 0) {
                const int jp = j - 1;
                const int di = jp / 9, dj = (jp / 3) % 3, dk = jp % 3;
                const int tt = t + di - 2, yy = y + dj - 2, xx = x + dk - 2;
                row = (tt >= 0 && yy >= 0 && xx >= 0)
                    ? 1 + tt * SDIM * SDIM + yy * SDIM + xx : 0;
            }
            vb[u] = *(const ushort8*)(KVb + (size_t)row * 1024 + 512 + lane * 8);
        }
        #pragma unroll
        for (int u = 0; u < 7; ++u) {
            const int j = b * 7 + u;
            bool valid = true;
            if (j != 0) {
                const int jp = j - 1;
                const int di = jp / 9, dj = (jp / 3) % 3, dk = jp % 3;
                valid = (t + di - 2 >= 0) && (y + dj - 2 >= 0) && (x + dk - 2 >= 0);
            }
            const float w = valid ? mixed_s[wave][g * NJ + j] : 0.f;
            #pragma unroll
            for (int e = 0; e < 8; ++e) acc8[e] += w * bf2f(vb[u][e]);
        }
    }

    unsigned short o[8];
    #pragma unroll
    for (int e = 0; e < 8; ++e) o[e] = f2bf(acc8[e]);
    *(ushort8*)(O + (size_t)qrow * DM + lane * 8) = *(const ushort8*)o;

    if (i == 0) {
        const ushort8 vb0 = *(const ushort8*)(KVb + 512 + lane * 8);
        *(ushort8*)(O + lane * 8) = vb0;
    }
}

// ---------------------------------------------------------------------------
extern "C" void kernel_launch(void* const* d_in, const int* in_sizes, int n_in,
                              void* d_out, int out_size, void* d_ws, size_t ws_size,
                              hipStream_t stream)
{
    const float* x    = (const float*)d_in[0];
    const float* Wq   = (const float*)d_in[1];
    const float* Wkv  = (const float*)d_in[2];
    const float* W_th = (const float*)d_in[3];
    const float* Wout = (const float*)d_in[4];
    const float* bout = (const float*)d_in[5];
    const float* ax1  = (const float*)d_in[6];
    const float* ax2  = (const float*)d_in[7];
    const float* ax3  = (const float*)d_in[8];
    float* out = (float*)d_out;

    char* p = (char*)d_ws;
    float* Qf = (float*)p;                       p += (size_t)NTOK * DM * 4;
    __hip_bfloat16* KVb   = (__hip_bfloat16*)p;  p += (size_t)NTOK * 2 * DM * 2;
    __hip_bfloat16* Ob    = (__hip_bfloat16*)p;  p += (size_t)NTOK * DM * 2;
    __hip_bfloat16* Wqkvt = (__hip_bfloat16*)p;  p += (size_t)3 * DM * DM * 2;
    __hip_bfloat16* Woutt = (__hip_bfloat16*)p;  p += (size_t)DM * DM * 2;
    __hip_bfloat16* xb    = (__hip_bfloat16*)p;  p += (size_t)NTOK * DM * 2;

    const dim3 blk(256);

    prep_w<<<2177, blk, 0, stream>>>(Wq, Wkv, Wout, x, Wqkvt, Woutt, xb);

    gemm_qkv<<<444, blk, 0, stream>>>(xb, Wqkvt, Qf, KVb, NTOK);

    attn_v4<<<dim3(NVID / 4), blk, 0, stream>>>(Qf, KVb, Ob, W_th, ax1, ax2, ax3);

    gemm_out<<<584, blk, 0, stream>>>(Ob, Woutt, out, NTOK, bout);
}

// Round 10
// 121.896 us; speedup vs baseline: 1.2789x; 1.0497x over previous
//
#include <hip/hip_runtime.h>
#include <hip/hip_bf16.h>

// Sparse 3DNA (causal), MI355X. Round 17:
// R16 base (127.96us). Scheduling-only changes, math identical:
// (1) gemm_qkv/gemm_out: LDS double-buffer + RAW s_barrier + counted
//     s_waitcnt vmcnt(N) (T3/T4-minimum). __syncthreads drains vmcnt(0)
//     every K-step (R2's dbuf failed for exactly this reason); counted
//     waits let next-tile DMA stay in flight across barriers.
// (2) attn: 1-deep batch pipeline (issue batch b+1 before computing b) and
//     V-batch-0 pre-issued before softmax; lgkmcnt(0)+raw barrier instead
//     of __syncthreads so pre-issued V loads survive the head-mix barriers.

constexpr int TFR   = 8;
constexpr int SDIM  = 24;
constexpr int NVID  = TFR * SDIM * SDIM;   // 4608
constexpr int NTOK  = NVID + 1;            // 4609
constexpr int NH    = 8;
constexpr int DM    = 512;
constexpr int NJ    = 28;

typedef __attribute__((ext_vector_type(8))) short bf16x8;
typedef __attribute__((ext_vector_type(8))) unsigned short ushort8;
typedef __attribute__((ext_vector_type(4))) float f32x4;

typedef const __attribute__((address_space(1))) unsigned int* gas_ptr;
typedef __attribute__((address_space(3))) unsigned int* las_ptr;

__device__ __forceinline__ float bf2f(unsigned short u) {
    return __uint_as_float((unsigned)u << 16);
}
__device__ __forceinline__ unsigned short f2bf(float f) {
    __hip_bfloat16 h = __float2bfloat16(f);
    return reinterpret_cast<unsigned short&>(h);
}

// ---------------------------------------------------------------------------
// prep: transpose+cast Wq/Wkv and Wout; straight cast x -> xb (bf16).
// ---------------------------------------------------------------------------
__global__ __launch_bounds__(256)
void prep_w(const float* __restrict__ Wq, const float* __restrict__ Wkv,
            const float* __restrict__ Wout, const float* __restrict__ x,
            __hip_bfloat16* __restrict__ Wqkvt, __hip_bfloat16* __restrict__ Woutt,
            __hip_bfloat16* __restrict__ xb)
{
    const int tid = threadIdx.x;
    int tb = blockIdx.x;

    if (tb >= 1024) {                       // ---- x cast: fp32 -> bf16 ----
        const size_t base = (size_t)(tb - 1024) * 2048 + (size_t)tid * 8;
        if (base < (size_t)NTOK * DM) {
            const float4 f0 = *(const float4*)(x + base);
            const float4 f1 = *(const float4*)(x + base + 4);
            unsigned short v[8] = { f2bf(f0.x), f2bf(f0.y), f2bf(f0.z), f2bf(f0.w),
                                    f2bf(f1.x), f2bf(f1.y), f2bf(f1.z), f2bf(f1.w) };
            *(ushort8*)(xb + base) = *(const ushort8*)v;
        }
        return;
    }

    __shared__ float t[32][33];
    const float* W; __hip_bfloat16* Wt; int Nd, tX, rowOff;
    if (tb < 256)      { W = Wq;   Wt = Wqkvt; Nd = 512;  tX = 16; rowOff = 0;   }
    else if (tb < 768) { tb -= 256; W = Wkv;  Wt = Wqkvt; Nd = 1024; tX = 32; rowOff = 512; }
    else               { tb -= 768; W = Wout; Wt = Woutt; Nd = 512;  tX = 16; rowOff = 0;   }
    const int n0 = (tb % tX) * 32, k0 = (tb / tX) * 32;
    const int r  = tid >> 3;
    const int c4 = (tid & 7) * 4;
    const float4 v = *(const float4*)(W + (size_t)(k0 + r) * Nd + n0 + c4);
    t[r][c4 + 0] = v.x; t[r][c4 + 1] = v.y; t[r][c4 + 2] = v.z; t[r][c4 + 3] = v.w;
    __syncthreads();
    #pragma unroll
    for (int j = 0; j < 4; ++j)
        Wt[(size_t)(rowOff + n0 + r) * 512 + k0 + c4 + j] = __float2bfloat16(t[c4 + j][r]);
}

// ---------------------------------------------------------------------------
// QKV GEMM: BM=BN=128, BK=64, 444 blocks, XCD-chunked. Double-buffered LDS
// with raw s_barrier + counted vmcnt(8): next-tile DMA stays in flight
// across the barrier; drain waits only the previous tile's 8 loads.
// ---------------------------------------------------------------------------
__global__ __launch_bounds__(256)
void gemm_qkv(const __hip_bfloat16* __restrict__ Ab, const __hip_bfloat16* __restrict__ Bt,
              float* __restrict__ Cq, __hip_bfloat16* __restrict__ Ckv, int M)
{
    constexpr int BM = 128, BN = 128, BK = 64, K = 512;
    __shared__ __align__(16) short As[2][BM * BK];
    __shared__ __align__(16) short Bs[2][BN * BK];

    const int tid  = threadIdx.x;
    const int bid  = blockIdx.x;
    const int xcd  = bid & 7, pos = bid >> 3;
    const int L    = (xcd < 4) ? xcd * 56 + pos : 224 + (xcd - 4) * 55 + pos;
    const int m0   = (L / 12) * BM;
    const int n0   = (L % 12) * BN;

    const int lane = tid & 63;
    const int wave = tid >> 6;
    const int wm   = (wave >> 1) * 64;
    const int wn   = (wave & 1) * 64;
    const int col  = lane & 15;
    const int quad = lane >> 4;

    f32x4 acc[4][4] = {};

    auto stage = [&](int buf, int k0) {
        #pragma unroll
        for (int it = 0; it < 4; ++it) {
            const int idx = it * 256 + tid;
            const int r   = idx >> 3;
            const int u   = (idx & 7) ^ (r & 7);
            const int gm  = (m0 + r < M) ? (m0 + r) : (M - 1);
            const __hip_bfloat16* gp = Ab + (size_t)gm * K + k0 + u * 8;
            __builtin_amdgcn_global_load_lds(
                (gas_ptr)gp, (las_ptr)&As[buf][(it * 256 + wave * 64) * 8], 16, 0, 0);
        }
        #pragma unroll
        for (int it = 0; it < 4; ++it) {
            const int idx = it * 256 + tid;
            const int r   = idx >> 3;
            const int u   = (idx & 7) ^ (r & 7);
            const __hip_bfloat16* gp = Bt + (size_t)(n0 + r) * K + k0 + u * 8;
            __builtin_amdgcn_global_load_lds(
                (gas_ptr)gp, (las_ptr)&Bs[buf][(it * 256 + wave * 64) * 8], 16, 0, 0);
        }
    };

    stage(0, 0);

    #pragma unroll
    for (int t = 0; t < K / BK; ++t) {
        const int cur = t & 1;
        if (t + 1 < K / BK) {
            stage(cur ^ 1, (t + 1) * BK);
            asm volatile("s_waitcnt vmcnt(8)" ::: "memory");   // cur's loads done
        } else {
            asm volatile("s_waitcnt vmcnt(0)" ::: "memory");
        }
        __builtin_amdgcn_s_barrier();

        #pragma unroll
        for (int ks = 0; ks < 2; ++ks) {
            bf16x8 af[4], bfr[4];
            #pragma unroll
            for (int mt = 0; mt < 4; ++mt) {
                const int r = wm + mt * 16 + col;
                const int u = (ks * 4 + quad) ^ (r & 7);
                af[mt] = *(const bf16x8*)(&As[cur][r * BK + u * 8]);
            }
            #pragma unroll
            for (int nt = 0; nt < 4; ++nt) {
                const int r = wn + nt * 16 + col;
                const int u = (ks * 4 + quad) ^ (r & 7);
                bfr[nt] = *(const bf16x8*)(&Bs[cur][r * BK + u * 8]);
            }
            #pragma unroll
            for (int mt = 0; mt < 4; ++mt)
                #pragma unroll
                for (int nt = 0; nt < 4; ++nt)
                    acc[mt][nt] = __builtin_amdgcn_mfma_f32_16x16x32_bf16(
                        af[mt], bfr[nt], acc[mt][nt], 0, 0, 0);
        }
        __builtin_amdgcn_s_barrier();   // all reads of buf[cur] done before overwrite
    }

    const bool isQ = (n0 < 512);
    #pragma unroll
    for (int mt = 0; mt < 4; ++mt) {
        #pragma unroll
        for (int r = 0; r < 4; ++r) {
            const int row = m0 + wm + mt * 16 + quad * 4 + r;
            if (row >= M) continue;
            #pragma unroll
            for (int nt = 0; nt < 4; ++nt) {
                const int cg = n0 + wn + nt * 16 + col;
                const float v = acc[mt][nt][r];
                if (isQ) Cq[(size_t)row * 512 + cg] = v * 0.125f;
                else     Ckv[(size_t)row * 1024 + (cg - 512)] = __float2bfloat16(v);
            }
        }
    }
}

// ---------------------------------------------------------------------------
// out-proj GEMM: BM=BN=64, 584 blocks, XCD-chunked. Same dbuf + counted
// vmcnt(4) structure (stage = 4 vmem instructions).
// ---------------------------------------------------------------------------
__global__ __launch_bounds__(256)
void gemm_out(const __hip_bfloat16* __restrict__ A, const __hip_bfloat16* __restrict__ Bt,
              float* __restrict__ C, int M, const float* __restrict__ bias)
{
    constexpr int BM = 64, BN = 64, BK = 64, K = 512;
    __shared__ __align__(16) short As[2][BM * BK];
    __shared__ __align__(16) short Bs[2][BN * BK];

    const int tid  = threadIdx.x;
    const int bid  = blockIdx.x;
    const int L    = (bid & 7) * 73 + (bid >> 3);   // 584 = 8*73 exact
    const int m0   = (L >> 3) * BM;
    const int n0   = (L & 7) * BN;
    const int lane = tid & 63;
    const int wave = tid >> 6;
    const int wm   = (wave >> 1) * 32;
    const int wn   = (wave & 1) * 32;
    const int col  = lane & 15;
    const int quad = lane >> 4;

    f32x4 acc[2][2] = {};

    auto stage = [&](int buf, int k0) {
        #pragma unroll
        for (int it = 0; it < 2; ++it) {
            const int idx = it * 256 + tid;
            const int r   = idx >> 3;
            const int u   = (idx & 7) ^ (r & 7);
            const int gm  = (m0 + r < M) ? (m0 + r) : (M - 1);
            const __hip_bfloat16* gp = A + (size_t)gm * K + k0 + u * 8;
            __builtin_amdgcn_global_load_lds(
                (gas_ptr)gp, (las_ptr)&As[buf][(it * 256 + wave * 64) * 8], 16, 0, 0);
        }
        #pragma unroll
        for (int it = 0; it < 2; ++it) {
            const int idx = it * 256 + tid;
            const int r   = idx >> 3;
            const int u   = (idx & 7) ^ (r & 7);
            const __hip_bfloat16* gp = Bt + (size_t)(n0 + r) * K + k0 + u * 8;
            __builtin_amdgcn_global_load_lds(
                (gas_ptr)gp, (las_ptr)&Bs[buf][(it * 256 + wave * 64) * 8], 16, 0, 0);
        }
    };

    stage(0, 0);

    #pragma unroll
    for (int t = 0; t < K / BK; ++t) {
        const int cur = t & 1;
        if (t + 1 < K / BK) {
            stage(cur ^ 1, (t + 1) * BK);
            asm volatile("s_waitcnt vmcnt(4)" ::: "memory");
        } else {
            asm volatile("s_waitcnt vmcnt(0)" ::: "memory");
        }
        __builtin_amdgcn_s_barrier();

        #pragma unroll
        for (int ks = 0; ks < 2; ++ks) {
            bf16x8 af[2], bfr[2];
            #pragma unroll
            for (int mt = 0; mt < 2; ++mt) {
                const int r = wm + mt * 16 + col;
                const int u = (ks * 4 + quad) ^ (r & 7);
                af[mt] = *(const bf16x8*)(&As[cur][r * BK + u * 8]);
            }
            #pragma unroll
            for (int nt = 0; nt < 2; ++nt) {
                const int r = wn + nt * 16 + col;
                const int u = (ks * 4 + quad) ^ (r & 7);
                bfr[nt] = *(const bf16x8*)(&Bs[cur][r * BK + u * 8]);
            }
            #pragma unroll
            for (int mt = 0; mt < 2; ++mt)
                #pragma unroll
                for (int nt = 0; nt < 2; ++nt)
                    acc[mt][nt] = __builtin_amdgcn_mfma_f32_16x16x32_bf16(
                        af[mt], bfr[nt], acc[mt][nt], 0, 0, 0);
        }
        __builtin_amdgcn_s_barrier();
    }

    #pragma unroll
    for (int mt = 0; mt < 2; ++mt) {
        #pragma unroll
        for (int r = 0; r < 4; ++r) {
            const int row = m0 + wm + mt * 16 + quad * 4 + r;
            if (row >= M) continue;
            #pragma unroll
            for (int nt = 0; nt < 2; ++nt) {
                const int cg = n0 + wn + nt * 16 + col;
                C[(size_t)row * 512 + cg] = acc[mt][nt][r] + bias[cg];
            }
        }
    }
}

// ---------------------------------------------------------------------------
// Attention v5: one wave per query, 4 queries/block; 7-load batches with
// 1-deep pipelining (issue b+1 before computing b); V-batch-0 pre-issued
// before softmax; raw lgkmcnt(0)+s_barrier (no vmcnt drain) at head-mix.
// ---------------------------------------------------------------------------
__device__ __forceinline__ void neigh(int j, int t, int y, int x,
                                      int& row, bool& val,
                                      int& di, int& dj, int& dk)
{
    if (j == 0) { row = 0; val = true; di = 0; dj = 0; dk = 0; return; }
    const int jp = j - 1;
    di = jp / 9; dj = (jp / 3) % 3; dk = jp % 3;
    const int tt = t + di - 2, yy = y + dj - 2, xx = x + dk - 2;
    val = (tt >= 0) && (yy >= 0) && (xx >= 0);
    row = val ? 1 + tt * SDIM * SDIM + yy * SDIM + xx : 0;
}

#define ISSUE_K(B, DST)                                                     \
    { _Pragma("unroll")                                                     \
      for (int u = 0; u < 7; ++u) {                                         \
        int row; bool val; int di, dj, dk;                                  \
        neigh((B) * 7 + u, t, y, x, row, val, di, dj, dk);                  \
        DST[u] = *(const ushort8*)(KVb + (size_t)row * 1024 + lane * 8);    \
      } }

#define DOTS_K(B, SRC)                                                      \
    { _Pragma("unroll")                                                     \
      for (int u = 0; u < 7; ++u) {                                         \
        const int j = (B) * 7 + u;                                          \
        int row; bool val; int di, dj, dk;                                  \
        neigh(j, t, y, x, row, val, di, dj, dk);                            \
        float p = 0.f;                                                      \
        _Pragma("unroll")                                                   \
        for (int e = 0; e < 8; ++e) p += bf2f(SRC[u][e]) * qf[e];           \
        p += __shfl_xor(p, 1);                                              \
        p += __shfl_xor(p, 2);                                              \
        p += __shfl_xor(p, 4);                                              \
        sim[j] = !val ? -1e30f                                              \
               : (j == 0 ? p : p + a1[di] + a2[dj] + a3[dk]);               \
      } }

#define ISSUE_V(B, DST)                                                     \
    { _Pragma("unroll")                                                     \
      for (int u = 0; u < 7; ++u) {                                         \
        int row; bool val; int di, dj, dk;                                  \
        neigh((B) * 7 + u, t, y, x, row, val, di, dj, dk);                  \
        DST[u] = *(const ushort8*)(KVb + (size_t)row * 1024 + 512 + lane * 8); \
      } }

#define ACC_V(B, SRC)                                                       \
    { _Pragma("unroll")                                                     \
      for (int u = 0; u < 7; ++u) {                                         \
        const int j = (B) * 7 + u;                                          \
        const float w = mixed_s[wave][g * NJ + j];                          \
        _Pragma("unroll")                                                   \
        for (int e = 0; e < 8; ++e) acc8[e] += w * bf2f(SRC[u][e]);         \
      } }

__global__ __launch_bounds__(256, 3)
void attn_v5(const float* __restrict__ Q, const __hip_bfloat16* __restrict__ KVb,
             __hip_bfloat16* __restrict__ O,
             const float* __restrict__ W_th,
             const float* __restrict__ ax1, const float* __restrict__ ax2,
             const float* __restrict__ ax3)
{
    __shared__ float attn_s[4][NH * NJ];
    __shared__ float mixed_s[4][NH * NJ];

    const int tid  = threadIdx.x;
    const int wave = tid >> 6;
    const int lane = tid & 63;
    const int g    = lane >> 3;
    const int s    = lane & 7;
    const int bsw  = (blockIdx.x & 7) * (NVID / 4 / 8) + (blockIdx.x >> 3);
    const int i    = __builtin_amdgcn_readfirstlane(bsw * 4 + wave);
    const int qrow = i + 1;

    const int t  = i / (SDIM * SDIM);
    const int rm = i % (SDIM * SDIM);
    const int y  = rm / SDIM;
    const int x  = rm % SDIM;

    float qf[8];
    {
        const float4 q0 = *(const float4*)(Q + (size_t)qrow * DM + lane * 8);
        const float4 q1 = *(const float4*)(Q + (size_t)qrow * DM + lane * 8 + 4);
        qf[0] = q0.x; qf[1] = q0.y; qf[2] = q0.z; qf[3] = q0.w;
        qf[4] = q1.x; qf[5] = q1.y; qf[6] = q1.z; qf[7] = q1.w;
    }
    float a1[3], a2[3], a3[3];
    #pragma unroll
    for (int d = 0; d < 3; ++d) {
        a1[d] = ax1[d * NH + g];
        a2[d] = ax2[d * NH + g];
        a3[d] = ax3[d * NH + g];
    }

    // ---- Phase 1: QK^T, pipelined batches ---------------------------------
    float sim[NJ];
    ushort8 bufA[7], bufB[7];
    ISSUE_K(0, bufA);
    ISSUE_K(1, bufB);
    DOTS_K(0, bufA);
    ISSUE_K(2, bufA);
    DOTS_K(1, bufB);
    ISSUE_K(3, bufB);
    DOTS_K(2, bufA);
    DOTS_K(3, bufB);

    // ---- pre-issue V batch 0 (hides under softmax + mix barriers) ---------
    ISSUE_V(0, bufA);

    // ---- softmax (per head, in registers) ---------------------------------
    float m = -1e30f;
    #pragma unroll
    for (int j = 0; j < NJ; ++j) m = fmaxf(m, sim[j]);
    float ssum = 0.f;
    #pragma unroll
    for (int j = 0; j < NJ; ++j) { sim[j] = __expf(sim[j] - m); ssum += sim[j]; }
    const float inv = 1.f / ssum;
    #pragma unroll
    for (int j = 0; j < NJ; ++j) sim[j] *= inv;

    // ---- head mix via LDS; raw barriers (no vmcnt drain) ------------------
    if (s == 0) {
        #pragma unroll
        for (int u = 0; u < 7; ++u) {
            f32x4 v4 = { sim[4*u], sim[4*u+1], sim[4*u+2], sim[4*u+3] };
            *(f32x4*)(&attn_s[wave][g * NJ + 4 * u]) = v4;
        }
    }
    asm volatile("s_waitcnt lgkmcnt(0)" ::: "memory");
    __builtin_amdgcn_s_barrier();

    if (tid < NH * NJ) {
        const int h = tid / NJ, j = tid % NJ;
        #pragma unroll
        for (int q = 0; q < 4; ++q) {
            float acc = 0.f;
            #pragma unroll
            for (int gg = 0; gg < NH; ++gg)
                acc += W_th[h * NH + gg] * attn_s[q][gg * NJ + j];
            mixed_s[q][h * NJ + j] = acc;
        }
    }
    asm volatile("s_waitcnt lgkmcnt(0)" ::: "memory");
    __builtin_amdgcn_s_barrier();

    // ---- Phase 2: PV, pipelined (batch 0 already in flight) ---------------
    float acc8[8] = {};
    ISSUE_V(1, bufB);
    ACC_V(0, bufA);
    ISSUE_V(2, bufA);
    ACC_V(1, bufB);
    ISSUE_V(3, bufB);
    ACC_V(2, bufA);
    ACC_V(3, bufB);

    unsigned short o[8];
    #pragma unroll
    for (int e = 0; e < 8; ++e) o[e] = f2bf(acc8[e]);
    *(ushort8*)(O + (size_t)qrow * DM + lane * 8) = *(const ushort8*)o;

    if (i == 0) {
        const ushort8 vb0 = *(const ushort8*)(KVb + 512 + lane * 8);
        *(ushort8*)(O + lane * 8) = vb0;
    }
}

// ---------------------------------------------------------------------------
extern "C" void kernel_launch(void* const* d_in, const int* in_sizes, int n_in,
                              void* d_out, int out_size, void* d_ws, size_t ws_size,
                              hipStream_t stream)
{
    const float* x    = (const float*)d_in[0];
    const float* Wq   = (const float*)d_in[1];
    const float* Wkv  = (const float*)d_in[2];
    const float* W_th = (const float*)d_in[3];
    const float* Wout = (const float*)d_in[4];
    const float* bout = (const float*)d_in[5];
    const float* ax1  = (const float*)d_in[6];
    const float* ax2  = (const float*)d_in[7];
    const float* ax3  = (const float*)d_in[8];
    float* out = (float*)d_out;

    char* p = (char*)d_ws;
    float* Qf = (float*)p;                       p += (size_t)NTOK * DM * 4;
    __hip_bfloat16* KVb   = (__hip_bfloat16*)p;  p += (size_t)NTOK * 2 * DM * 2;
    __hip_bfloat16* Ob    = (__hip_bfloat16*)p;  p += (size_t)NTOK * DM * 2;
    __hip_bfloat16* Wqkvt = (__hip_bfloat16*)p;  p += (size_t)3 * DM * DM * 2;
    __hip_bfloat16* Woutt = (__hip_bfloat16*)p;  p += (size_t)DM * DM * 2;
    __hip_bfloat16* xb    = (__hip_bfloat16*)p;  p += (size_t)NTOK * DM * 2;

    const dim3 blk(256);

    prep_w<<<2177, blk, 0, stream>>>(Wq, Wkv, Wout, x, Wqkvt, Woutt, xb);

    gemm_qkv<<<444, blk, 0, stream>>>(xb, Wqkvt, Qf, KVb, NTOK);

    attn_v5<<<dim3(NVID / 4), blk, 0, stream>>>(Qf, KVb, Ob, W_th, ax1, ax2, ax3);

    gemm_out<<<584, blk, 0, stream>>>(Ob, Woutt, out, NTOK, bout);
}